// Round 4
// baseline (77.248 us; speedup 1.0000x reference)
//
#include <hip/hip_runtime.h>

// GMP (generalized memory polynomial), B=32, T=4096, M=11, DEG=5 (K=4 powers).
//
// out[b,t] = sum_{m=0..10} xc[b,t+m-10] *
//              ( W0[m] + sum_{k=1..4} sum_{l=0..10} |xc[b,t+l+m-20]|^k * W1[k-1,l,m] )
// with xc zero-padded for negative time indices.
// W0[m] = Weight[m]; W1[k,l,m] = Weight[11 + k*121 + l*11 + m].
//
// 8-way split: block = 512 threads = 8 waves; wave role r -> power channel
// q = r&3 (|x|^(q+1)) x l-half h = r>>2 (l in 0..5 or 6..10). Per-wave weight
// slab is 55-66 floats -> fully SGPR-resident (no in-loop s_load reloads);
// per-thread FMA chain ~80; power window only 16 entries. 2048 blocks x 8
// waves = 4 blocks/CU x 8 waves = full 32 waves/CU occupancy.

#define GMP_M 11
#define GMP_T 4096
#define GMP_B 32
#define TILE 64
#define HALO 20   // 2*(M-1)

__global__ __launch_bounds__(512) void gmp_kernel(const float* __restrict__ x,
                                                  const float* __restrict__ W,
                                                  float* __restrict__ out) {
    const int b   = blockIdx.y;
    const int t0  = blockIdx.x * TILE;
    const int tid = threadIdx.x;
    const int lt  = tid & 63;
    // wave-uniform role: q = power channel (0..3), h = l-half (0..1)
    const int r   = __builtin_amdgcn_readfirstlane(tid >> 6);
    const int q   = r & 3;
    const int h   = r >> 2;

    __shared__ float2 xs[TILE + HALO];      // xc[b, t0-20+i]
    __shared__ float  pk[4][TILE + HALO];   // SoA power channels: a, a^2, a^3, a^4
    __shared__ float2 psum[7 * TILE];       // partials from waves 1..7

    const float2* xb = (const float2*)(x + (size_t)b * GMP_T * 2);

    for (int i = tid; i < TILE + HALO; i += 512) {
        int g = t0 - HALO + i;
        float2 v = make_float2(0.f, 0.f);
        if (g >= 0) v = xb[g];              // g <= t0+63 <= T-1 always
        xs[i] = v;
        float r2 = v.x * v.x + v.y * v.y;
        float a  = sqrtf(r2);
        pk[0][i] = a;
        pk[1][i] = r2;
        pk[2][i] = r2 * a;
        pk[3][i] = r2 * r2;
    }
    __syncthreads();

    // This role's 16-entry power window: covers l+m for its l-half.
    // h=0: l+m in 0..15 (base 0); h=1: l+m in 6..20 (base 5, s=1..15).
    const int base = 5 * h;
    float P[16];
#pragma unroll
    for (int s = 0; s < 16; ++s) P[s] = pk[q][lt + base + s];

    // Weight slab for this role: W1[q, l, m] for its l-half (<=66 floats).
    const float* __restrict__ Wq = W + GMP_M + q * 121;
    const int l_lo = h ? 6 : 0;
    const int l_hi = h ? GMP_M : 6;

    float2 acc = make_float2(0.f, 0.f);
#pragma unroll
    for (int m = 0; m < GMP_M; ++m) {
        float gm = (r == 0) ? W[m] : 0.f;   // W0 tap term only on wave 0
#pragma unroll
        for (int l = l_lo; l < l_hi; ++l)
            gm += P[l + m - base] * Wq[l * 11 + m];
        float2 xv = xs[lt + m + (GMP_M - 1)];   // xc[b, t+m-10]
        acc.x += xv.x * gm;
        acc.y += xv.y * gm;
    }

    if (r) {                                // wave-uniform branch
        psum[(r - 1) * TILE + lt] = acc;
    }
    __syncthreads();
    if (r == 0) {
        float2 o = acc;
#pragma unroll
        for (int j = 0; j < 7; ++j) {
            float2 p = psum[j * TILE + lt];
            o.x += p.x;
            o.y += p.y;
        }
        float2* ob = (float2*)(out + ((size_t)b * GMP_T + t0) * 2);
        ob[lt] = o;
    }
}

extern "C" void kernel_launch(void* const* d_in, const int* in_sizes, int n_in,
                              void* d_out, int out_size, void* d_ws, size_t ws_size,
                              hipStream_t stream) {
    (void)in_sizes; (void)n_in; (void)d_ws; (void)ws_size; (void)out_size;
    const float* x = (const float*)d_in[0];
    // d_in[1] is h_0 (unused by the reference computation)
    const float* W = (const float*)d_in[2];
    float* out = (float*)d_out;

    dim3 grid(GMP_T / TILE, GMP_B, 1);   // 64 x 32 = 2048 blocks
    dim3 block(512, 1, 1);
    gmp_kernel<<<grid, block, 0, stream>>>(x, W, out);
}

// Round 5
// 62.468 us; speedup vs baseline: 1.2366x; 1.2366x over previous
//
#include <hip/hip_runtime.h>

// GMP (generalized memory polynomial), B=32, T=4096, M=11, DEG=5 (K=4 powers).
//
// out[b,t] = sum_{m=0..10} xc[b,t+m-10] *
//              ( W0[m] + sum_{k=1..4} sum_{l=0..10} |xc[b,t+l+m-20]|^k * W1[k-1,l,m] )
// with xc zero-padded for negative time indices.
// W0[m] = Weight[m]; W1[k,l,m] = Weight[11 + k*121 + l*11 + m].
//
// 8-way split: block = 512 threads = 8 waves; wave role r -> power channel
// q = r&3 (|x|^(q+1)) x l-half h = r>>2 (l in 0..5 or 6..10).
// ROUND-4 BUG FIX: the l-loop bounds are now COMPILE-TIME template params —
// round 4 used runtime bounds, which blocked unrolling and demoted the P[16]
// window to scratch (dynamic indexing), costing +14 us. With constant bounds
// P stays in VGPRs and the per-wave weight slab (55-66 floats) is
// SGPR-resident. 2048 blocks x 8 waves = 32 waves/CU (full occupancy).

#define GMP_M 11
#define GMP_T 4096
#define GMP_B 32
#define TILE 64
#define HALO 20   // 2*(M-1)

template <int L_LO, int L_HI, int BASE>
__device__ __forceinline__ float2 gmp_partial(const float (&P)[16],
                                              const float2* __restrict__ xs,
                                              const float* __restrict__ Wq,
                                              const float* __restrict__ W0,
                                              int lt) {
    float2 acc = make_float2(0.f, 0.f);
#pragma unroll
    for (int m = 0; m < GMP_M; ++m) {
        float gm = W0 ? W0[m] : 0.f;        // W0 tap term (wave 0 only)
#pragma unroll
        for (int l = L_LO; l < L_HI; ++l)
            gm += P[l + m - BASE] * Wq[l * 11 + m];
        float2 xv = xs[lt + m + (GMP_M - 1)];   // xc[b, t+m-10]
        acc.x += xv.x * gm;
        acc.y += xv.y * gm;
    }
    return acc;
}

__global__ __launch_bounds__(512) void gmp_kernel(const float* __restrict__ x,
                                                  const float* __restrict__ W,
                                                  float* __restrict__ out) {
    const int b   = blockIdx.y;
    const int t0  = blockIdx.x * TILE;
    const int tid = threadIdx.x;
    const int lt  = tid & 63;
    // wave-uniform role: q = power channel (0..3), h = l-half (0..1)
    const int r   = __builtin_amdgcn_readfirstlane(tid >> 6);
    const int q   = r & 3;
    const int h   = r >> 2;

    __shared__ float2 xs[TILE + HALO];      // xc[b, t0-20+i]
    __shared__ float  pk[4][TILE + HALO];   // SoA power channels: a, a^2, a^3, a^4
    __shared__ float2 psum[7 * TILE];       // partials from waves 1..7

    const float2* xb = (const float2*)(x + (size_t)b * GMP_T * 2);

    for (int i = tid; i < TILE + HALO; i += 512) {
        int g = t0 - HALO + i;
        float2 v = make_float2(0.f, 0.f);
        if (g >= 0) v = xb[g];              // g <= t0+63 <= T-1 always
        xs[i] = v;
        float r2 = v.x * v.x + v.y * v.y;
        float a  = sqrtf(r2);
        pk[0][i] = a;
        pk[1][i] = r2;
        pk[2][i] = r2 * a;
        pk[3][i] = r2 * r2;
    }
    __syncthreads();

    // This role's 16-entry power window (VGPR-resident; constant indexing only).
    // h=0 uses indices l+m in 0..15 (base 0); h=1 uses l+m-5 in 1..15 (base 5).
    const int base = 5 * h;
    float P[16];
#pragma unroll
    for (int s = 0; s < 16; ++s) P[s] = pk[q][lt + base + s];

    // Weight slab for this role: W1[q, l, m] for its l-half (<=66 floats).
    const float* __restrict__ Wq = W + GMP_M + q * 121;

    float2 acc;
    if (h == 0)
        acc = gmp_partial<0, 6, 0>(P, xs, Wq, (r == 0) ? W : nullptr, lt);
    else
        acc = gmp_partial<6, GMP_M, 5>(P, xs, Wq, nullptr, lt);

    if (r) {                                // wave-uniform branch
        psum[(r - 1) * TILE + lt] = acc;
    }
    __syncthreads();
    if (r == 0) {
        float2 o = acc;
#pragma unroll
        for (int j = 0; j < 7; ++j) {
            float2 p = psum[j * TILE + lt];
            o.x += p.x;
            o.y += p.y;
        }
        float2* ob = (float2*)(out + ((size_t)b * GMP_T + t0) * 2);
        ob[lt] = o;
    }
}

extern "C" void kernel_launch(void* const* d_in, const int* in_sizes, int n_in,
                              void* d_out, int out_size, void* d_ws, size_t ws_size,
                              hipStream_t stream) {
    (void)in_sizes; (void)n_in; (void)d_ws; (void)ws_size; (void)out_size;
    const float* x = (const float*)d_in[0];
    // d_in[1] is h_0 (unused by the reference computation)
    const float* W = (const float*)d_in[2];
    float* out = (float*)d_out;

    dim3 grid(GMP_T / TILE, GMP_B, 1);   // 64 x 32 = 2048 blocks
    dim3 block(512, 1, 1);
    gmp_kernel<<<grid, block, 0, stream>>>(x, W, out);
}